// Round 12
// baseline (167.454 us; speedup 1.0000x reference)
//
#include <hip/hip_runtime.h>
#include <math.h>

typedef float vf2 __attribute__((ext_vector_type(2)));

// ---------------- packed dual-fp32 helpers (VOP3P) ----------------
__device__ __forceinline__ vf2 pk_fma(vf2 a, vf2 b, vf2 c) {
    vf2 d;
    asm("v_pk_fma_f32 %0, %1, %2, %3" : "=v"(d) : "v"(a), "v"(b), "v"(c));
    return d;
}
__device__ __forceinline__ vf2 pk_mul(vf2 a, vf2 b) {
    vf2 d;
    asm("v_pk_mul_f32 %0, %1, %2" : "=v"(d) : "v"(a), "v"(b));
    return d;
}

// ================= streaming level-0 kernel =================
// Thread owns output column ox = c0 + tid. Streams input rows in chunks of
// 11 (fully unrolled -> mod-11 register ring has static indices). Per row:
// h = 12-tap parity-shifted horizontal conv read directly from the staged
// row; scatter h into 11 pending vertical accumulators (registers). Output
// emitted (SSIM) when its 11th tap arrives. LDS holds ONLY the 11-row input
// window (+ping-pong carry row for pooling). 2 barriers / 11 rows.
// Weights PRE-BROADCAST {w,w} (op_sel variant was numerically wrong, r10).
// SEG=64 (r10-proven; SEG=32 regressed: halo overhead + prologue domination).
#define L0_H 512
#define L0_HOUT 502
#define L0_HP 256
#define L0_SEG 64
#define L0_NCHUNK 7                 // ceil((SEG+10)/11)
#define ROWW 536                    // 268 staged cols x (P,Q) words
#define NQ 134                      // quads per row
#define CARRY_BASE (11 * ROWW)      // 5896
#define STREAM_WORDS (CARRY_BASE + 2 * ROWW)   // + ping-pong carry

__global__ __launch_bounds__(256)
void msssim_stream_l0(const float* __restrict__ img1,
                      const float* __restrict__ img2,
                      double* __restrict__ sums,
                      float* __restrict__ poolP, float* __restrict__ poolQ)
{
    __shared__ __align__(16) float buf[STREAM_WORDS];
    __shared__ float wred[4][2];

    const float gs[11] = {0.00102838f, 0.00759875f, 0.03600077f, 0.10936070f,
                          0.21300554f, 0.26601173f, 0.21300554f, 0.10936070f,
                          0.03600077f, 0.00759875f, 0.00102838f};

    const int tid = threadIdx.x;
    const int c0 = blockIdx.x * 256;          // strip base col
    const int oy0 = blockIdx.y * L0_SEG;      // seg base output row
    const long long plane = (long long)blockIdx.z * L0_H * L0_H;
    const long long pplane = (long long)blockIdx.z * L0_HP * L0_HP;
    const bool colok = (c0 + tid) < L0_HOUT;

    // ---- weights: h taps parity-shifted, PRE-BROADCAST {w,w}
    const int par = tid & 1;
    vf2 wbl[6], wbh[6];
    #pragma unroll
    for (int u = 0; u < 6; ++u) {
        const float we_lo = (2 * u < 11) ? gs[2 * u] : 0.f;
        const float wo_lo = (2 * u >= 1) ? gs[2 * u - 1] : 0.f;
        const float we_hi = (2 * u + 1 < 11) ? gs[2 * u + 1] : 0.f;
        const float wo_hi = gs[2 * u];
        const float wl = par ? wo_lo : we_lo;
        const float wh = par ? wo_hi : we_hi;
        wbl[u].x = wl; wbl[u].y = wl;
        wbh[u].x = wh; wbh[u].y = wh;
    }
    vf2 wgv[6];
    #pragma unroll
    for (int k = 0; k < 6; ++k) { wgv[k].x = gs[k]; wgv[k].y = gs[k]; }

    // ---- staging slots: 1474 quads (11 rows x 134), 6 slots/thread
    int rowS[6], colS[6], ldsoff[6], rHS[6];
    #pragma unroll
    for (int t = 0; t < 6; ++t) {
        const int s = tid + 256 * t;
        if (s < 11 * NQ) {
            const int r = s / NQ, q = s - NQ * r;
            rowS[t] = r;
            colS[t] = c0 + 2 * q;
            ldsoff[t] = r * ROWW + q * 4;
            rHS[t] = r * L0_H;
        } else { rowS[t] = -1; colS[t] = 0; ldsoff[t] = 0; rHS[t] = 0; }
    }

    float4 pf[6];
    auto prefetch = [&](int ybase) {
        const int yH = ybase * L0_H;
        #pragma unroll
        for (int t = 0; t < 6; ++t) {
            float2 a = make_float2(0.f, 0.f), b = make_float2(0.f, 0.f);
            if (rowS[t] >= 0) {
                const int y = ybase + rowS[t];
                if (y < L0_H && colS[t] < L0_H) {
                    const long long idx = plane + yH + rHS[t] + colS[t];
                    a = *(const float2*)(img1 + idx);
                    b = *(const float2*)(img2 + idx);
                }
            }
            pf[t] = make_float4(a.x + b.x, a.x - b.x, a.y + b.y, a.y - b.y);
        }
    };
    auto stage_write = [&]() {
        #pragma unroll
        for (int t = 0; t < 6; ++t)
            if (rowS[t] >= 0) *(float4*)&buf[ldsoff[t]] = pf[t];
    };

    // prologue: chunk 0
    prefetch(oy0);
    stage_write();
    __syncthreads();

    // ---- pending register ring
    vf2 pd_pq[11], pd_sq[11];
    #pragma unroll
    for (int s = 0; s < 11; ++s) { pd_pq[s] = (vf2){0.f, 0.f}; pd_sq[s] = (vf2){0.f, 0.f}; }

    const int qb4 = (tid >> 1) * 4;
    const float C1 = 4.0e-4f, C2 = 3.6e-3f;
    float ssim_acc = 0.f, cs_acc = 0.f;

    for (int c = 0; c < L0_NCHUNK; ++c) {
        const int cs = oy0 + 11 * c;          // first input row of chunk
        const bool more = (c + 1 < L0_NCHUNK);

        if (more) prefetch(cs + 11);          // loads hide under compute

        // ---- fused pool of (P,Q) rows — all 256 threads (2 groups of 128)
        {
            const int pxl = tid & 127;
            const int grp = tid >> 7;
            const int px = (c0 >> 1) + pxl;
            const int t4 = pxl * 4;
            #pragma unroll
            for (int pi = 0; pi < 5; ++pi) {
                if ((pi & 1) == grp) {
                    const int jp = (cs & 1) + 2 * pi;
                    const int py = (cs + jp) >> 1;
                    if (py < L0_HP) {
                        const float4 v0 = *(const float4*)&buf[jp * ROWW + t4];
                        const float4 v1 = *(const float4*)&buf[(jp + 1) * ROWW + t4];
                        poolP[pplane + py * L0_HP + px] = 0.25f * (v0.x + v0.z + v1.x + v1.z);
                        poolQ[pplane + py * L0_HP + px] = 0.25f * (v0.y + v0.w + v1.y + v1.w);
                    }
                }
            }
            if (grp == 1 && c > 0 && (cs & 1)) {   // spanning pair (cs-1, cs)
                const int py = (cs - 1) >> 1;
                if (py < L0_HP) {
                    const float4 v0 = *(const float4*)&buf[CARRY_BASE + ((c - 1) & 1) * ROWW + t4];
                    const float4 v1 = *(const float4*)&buf[t4];
                    poolP[pplane + py * L0_HP + px] = 0.25f * (v0.x + v0.z + v1.x + v1.z);
                    poolQ[pplane + py * L0_HP + px] = 0.25f * (v0.y + v0.w + v1.y + v1.w);
                }
            }
        }
        if (((cs & 1) == 0) && more && tid < NQ) {   // next chunk spans: save last row
            *(float4*)&buf[CARRY_BASE + (c & 1) * ROWW + tid * 4] =
                *(const float4*)&buf[10 * ROWW + tid * 4];
        }

        // ---- 11 unrolled rows: h + register-ring v + emit
        #pragma unroll
        for (int j = 0; j < 11; ++j) {
            float4 q[6];
            const int rw = j * ROWW + qb4;
            #pragma unroll
            for (int u = 0; u < 6; ++u) q[u] = *(const float4*)&buf[rw + 4 * u];

            vf2 hpq = {0.f, 0.f}, hsq = {0.f, 0.f};
            #pragma unroll
            for (int u = 0; u < 6; ++u) {
                const vf2 elo = {q[u].x, q[u].y};
                const vf2 ehi = {q[u].z, q[u].w};
                const vf2 slo = pk_mul(elo, elo);
                const vf2 shi = pk_mul(ehi, ehi);
                hpq = pk_fma(wbl[u], elo, hpq);
                hpq = pk_fma(wbh[u], ehi, hpq);
                hsq = pk_fma(wbl[u], slo, hsq);
                hsq = pk_fma(wbh[u], shi, hsq);
            }
            #pragma unroll
            for (int k = 0; k < 11; ++k) {
                const int s = (j - k + 11) % 11;       // static
                const int m = (k <= 5) ? k : 10 - k;   // static
                pd_pq[s] = pk_fma(wgv[m], hpq, pd_pq[s]);
                pd_sq[s] = pk_fma(wgv[m], hsq, pd_sq[s]);
            }
            const int yrel = 11 * c + j;
            if (yrel >= 10) {
                const int s = (j + 1) % 11;            // static
                const int orow = yrel - 10;
                if (orow < L0_SEG && (oy0 + orow) < L0_HOUT && colok) {
                    const vf2 musq = pk_mul(pd_pq[s], pd_pq[s]);  // (cP^2,cQ^2)
                    const float sP = pd_sq[s].x - musq.x;
                    const float sQ = pd_sq[s].y - musq.y;
                    const float v1 = 0.5f * (sP - sQ) + C2;
                    const float v2 = 0.5f * (sP + sQ) + C2;
                    const float num1 = 0.5f * (musq.x - musq.y) + C1;
                    const float den1 = 0.5f * (musq.x + musq.y) + C1;
                    cs_acc += v1 * __builtin_amdgcn_rcpf(v2);
                    ssim_acc += num1 * v1 * __builtin_amdgcn_rcpf(den1 * v2);
                }
                pd_pq[s] = (vf2){0.f, 0.f};
                pd_sq[s] = (vf2){0.f, 0.f};
            }
        }

        __syncthreads();              // all buf reads done
        if (more) stage_write();      // write chunk c+1
        __syncthreads();              // buf ready
    }

    // ---- block reduction + atomics (level 0)
    #pragma unroll
    for (int off = 32; off > 0; off >>= 1) {
        ssim_acc += __shfl_down(ssim_acc, off);
        cs_acc   += __shfl_down(cs_acc, off);
    }
    const int wave = tid >> 6;
    if ((tid & 63) == 0) { wred[wave][0] = ssim_acc; wred[wave][1] = cs_acc; }
    __syncthreads();
    if (tid == 0) {
        atomicAdd(&sums[0], (double)(wred[0][0] + wred[1][0] + wred[2][0] + wred[3][0]));
        atomicAdd(&sums[5], (double)(wred[0][1] + wred[1][1] + wred[2][1] + wred[3][1]));
    }
}

// ================= phase kernel for levels 1-4 (r9/r10, verbatim) =================
#define TILE 32
#define IN_DIM 42
#define SCP 21
#define HALO 10
#define STAGE_WORDS (IN_DIM * SCP * 4)
#define SH 340
#define HB STAGE_WORDS
#define SMEM_WORDS (HB + 16 * SH)

__global__ __launch_bounds__(256)
void msssim_level_kernel(const float* __restrict__ src1,
                         const float* __restrict__ src2,
                         int H, int level, int tiles_per_seg, int pq_input,
                         double* __restrict__ sums,
                         float* __restrict__ pool1, float* __restrict__ pool2)
{
    __shared__ __align__(16) float smem[SMEM_WORDS];
    __shared__ float wred[4][2];

    const float g[11] = {0.00102838f, 0.00759875f, 0.03600077f, 0.10936070f,
                         0.21300554f, 0.26601173f, 0.21300554f, 0.10936070f,
                         0.03600077f, 0.00759875f, 0.00102838f};
    vf2 wg[11];
    #pragma unroll
    for (int k = 0; k < 11; ++k) { wg[k].x = g[k]; wg[k].y = g[k]; }

    const int tid = threadIdx.x;
    const int Hout = H - HALO;
    const int ntiles = (Hout + TILE - 1) / TILE;
    const int tstart = blockIdx.y * tiles_per_seg;
    const int tend = min(ntiles, tstart + tiles_per_seg);
    const int ox0 = blockIdx.x * TILE;
    const int Hp = H >> 1;
    const long long base = (long long)blockIdx.z * H * H;

    int rHS[4], rS[4], xS[4];
    #pragma unroll
    for (int t4 = 0; t4 < 4; ++t4) {
        const int s = tid + 256 * t4;
        if (s < IN_DIM * SCP) {
            const int r = s / SCP, cp = s - r * SCP;
            rS[t4] = r; rHS[t4] = r * H; xS[t4] = ox0 + 2 * cp;
        } else { rS[t4] = -1; rHS[t4] = 0; xS[t4] = 0; }
    }

    auto load_slot = [&](int t4, int ybase) -> float4 {
        float2 a = make_float2(0.f, 0.f), b = make_float2(0.f, 0.f);
        if (rS[t4] >= 0) {
            const int y = ybase + rS[t4], x = xS[t4];
            if (y < H && x < H) {
                const long long idx = base + (long long)ybase * H + rHS[t4] + x;
                a = *(const float2*)(src1 + idx);
                b = *(const float2*)(src2 + idx);
            }
        }
        if (pq_input) return make_float4(a.x, b.x, a.y, b.y);
        return make_float4(a.x + b.x, a.x - b.x, a.y + b.y, a.y - b.y);
    };

    float4 pref[4];
    {
        #pragma unroll
        for (int t4 = 0; t4 < 4; ++t4) pref[t4] = load_slot(t4, tstart * TILE);
        #pragma unroll
        for (int t4 = 0; t4 < 4; ++t4)
            if (rS[t4] >= 0) *(float4*)&smem[(tid + 256 * t4) * 4] = pref[t4];
    }
    __syncthreads();

    float ssim_acc = 0.f, cs_acc = 0.f;

    for (int tt = tstart; tt < tend; ++tt) {
        const int ty0 = tt * TILE;
        const bool more = (tt + 1 < tend);

        if (more) {
            #pragma unroll
            for (int t4 = 0; t4 < 4; ++t4) pref[t4] = load_slot(t4, ty0 + TILE);
        }

        if (pool1 != nullptr) {
            const int pr = tid >> 4, pc = tid & 15;
            const int py = (ty0 >> 1) + pr, px = (ox0 >> 1) + pc;
            if (py < Hp && px < Hp) {
                const float4 v0 = *(const float4*)&smem[(2 * pr * SCP + pc) * 4];
                const float4 v1 = *(const float4*)&smem[((2 * pr + 1) * SCP + pc) * 4];
                const long long ob = (long long)blockIdx.z * Hp * Hp + (long long)py * Hp + px;
                pool1[ob] = 0.25f * (v0.x + v0.z + v1.x + v1.z);
                pool2[ob] = 0.25f * (v0.y + v0.w + v1.y + v1.w);
            }
        }

        float4 hA[3], hBv[3];
        #pragma unroll
        for (int t = 0; t < 3; ++t) {
            const int p = tid + 256 * t;
            if (p < IN_DIM * 16) {
                const int r = p >> 4, m = p & 15;
                vf2 Apq = {0.f, 0.f}, Asq = {0.f, 0.f};
                vf2 Bpq = {0.f, 0.f}, Bsq = {0.f, 0.f};
                #pragma unroll
                for (int jj = 0; jj < 6; ++jj) {
                    const float4 v = *(const float4*)&smem[(r * SCP + m + jj) * 4];
                    const vf2 lo = {v.x, v.y};
                    const vf2 hi = {v.z, v.w};
                    const vf2 losq = pk_mul(lo, lo);
                    const vf2 hisq = pk_mul(hi, hi);
                    Apq = pk_fma(wg[2 * jj], lo, Apq);
                    Asq = pk_fma(wg[2 * jj], losq, Asq);
                    if (jj >= 1) {
                        Bpq = pk_fma(wg[2 * jj - 1], lo, Bpq);
                        Bsq = pk_fma(wg[2 * jj - 1], losq, Bsq);
                    }
                    if (jj <= 4) {
                        Apq = pk_fma(wg[2 * jj + 1], hi, Apq);
                        Asq = pk_fma(wg[2 * jj + 1], hisq, Asq);
                    }
                    Bpq = pk_fma(wg[2 * jj], hi, Bpq);
                    Bsq = pk_fma(wg[2 * jj], hisq, Bsq);
                }
                hA[t]  = make_float4(Apq.x, Apq.y, Asq.x, Asq.y);
                hBv[t] = make_float4(Bpq.x, Bpq.y, Bsq.x, Bsq.y);
            }
        }
        __syncthreads();

        #pragma unroll
        for (int t = 0; t < 3; ++t) {
            const int p = tid + 256 * t;
            if (p < IN_DIM * 16) {
                const int r = p >> 4, m = p & 15;
                const int hb = HB + m * SH + r * 8;
                *(float4*)&smem[hb]     = hA[t];
                *(float4*)&smem[hb + 4] = hBv[t];
            }
        }
        if (more) {
            #pragma unroll
            for (int t4 = 0; t4 < 4; ++t4)
                if (rS[t4] >= 0) *(float4*)&smem[(tid + 256 * t4) * 4] = pref[t4];
        }
        __syncthreads();

        const int tx = tid & 31, rg = tid >> 5;
        const int r0 = rg * 4;
        const int m = tx >> 1, par = tx & 1;
        const int hb = HB + m * SH + par * 4;

        vf2 accPQ[4], accSQ[4];
        #pragma unroll
        for (int o = 0; o < 4; ++o) {
            accPQ[o] = (vf2){0.f, 0.f};
            accSQ[o] = (vf2){0.f, 0.f};
        }
        #pragma unroll
        for (int i = 0; i < 14; ++i) {
            const float4 h4 = *(const float4*)&smem[hb + (r0 + i) * 8];
            const vf2 ppq = {h4.x, h4.y};
            const vf2 psq = {h4.z, h4.w};
            #pragma unroll
            for (int o = 0; o < 4; ++o) {
                const int k = i - o;
                if (k >= 0 && k <= 10) {
                    accPQ[o] = pk_fma(wg[k], ppq, accPQ[o]);
                    accSQ[o] = pk_fma(wg[k], psq, accSQ[o]);
                }
            }
        }

        const float C1 = 4.0e-4f;
        const float C2 = 3.6e-3f;
        const int ox = ox0 + tx;
        #pragma unroll
        for (int o = 0; o < 4; ++o) {
            const int oy = ty0 + r0 + o;
            if (oy < Hout && ox < Hout) {
                const vf2 musq = pk_mul(accPQ[o], accPQ[o]);
                const float sP = accSQ[o].x - musq.x;
                const float sQ = accSQ[o].y - musq.y;
                const float v1 = 0.5f * (sP - sQ) + C2;
                const float v2 = 0.5f * (sP + sQ) + C2;
                const float num1 = 0.5f * (musq.x - musq.y) + C1;
                const float den1 = 0.5f * (musq.x + musq.y) + C1;
                cs_acc += v1 * __builtin_amdgcn_rcpf(v2);
                ssim_acc += num1 * v1 * __builtin_amdgcn_rcpf(den1 * v2);
            }
        }
    }

    #pragma unroll
    for (int off = 32; off > 0; off >>= 1) {
        ssim_acc += __shfl_down(ssim_acc, off);
        cs_acc   += __shfl_down(cs_acc, off);
    }
    const int wave = tid >> 6;
    if ((tid & 63) == 0) { wred[wave][0] = ssim_acc; wred[wave][1] = cs_acc; }
    __syncthreads();
    if (tid == 0) {
        const float s = wred[0][0] + wred[1][0] + wred[2][0] + wred[3][0];
        const float c = wred[0][1] + wred[1][1] + wred[2][1] + wred[3][1];
        atomicAdd(&sums[level],     (double)s);
        atomicAdd(&sums[5 + level], (double)c);
    }
}

// -------------------- final combine --------------------
__global__ void msssim_final_kernel(const double* __restrict__ sums,
                                    float* __restrict__ out)
{
    if (threadIdx.x == 0 && blockIdx.x == 0) {
        const double W[5] = {0.0448, 0.2856, 0.3001, 0.2363, 0.1333};
        const int Houts[5] = {502, 246, 118, 54, 22};
        double mssim[5], mcs[5];
        for (int l = 0; l < 5; ++l) {
            const double cnt = 48.0 * (double)Houts[l] * (double)Houts[l];
            mssim[l] = (sums[l]     / cnt + 1.0) * 0.5;
            mcs[l]   = (sums[5 + l] / cnt + 1.0) * 0.5;
        }
        const double p2 = pow(mssim[4], W[4]);
        double prod = 1.0;
        for (int l = 0; l < 4; ++l) prod *= pow(mcs[l], W[l]) * p2;
        out[0] = (float)(1.0 - prod);
    }
}

// -------------------- launch --------------------
extern "C" void kernel_launch(void* const* d_in, const int* in_sizes, int n_in,
                              void* d_out, int out_size, void* d_ws, size_t ws_size,
                              hipStream_t stream)
{
    const float* img1 = (const float*)d_in[0];
    const float* img2 = (const float*)d_in[1];
    float* out = (float*)d_out;
    (void)in_sizes; (void)n_in; (void)out_size; (void)ws_size;

    char* ws = (char*)d_ws;
    double* sums = (double*)ws;                      // 10 doubles
    float* X1 = (float*)(ws + 256);                  // P planes (L1 input)
    float* X2 = X1 + 3145728;                        // Q planes
    float* Y1 = X2 + 3145728;
    float* Y2 = Y1 + 786432;

    hipMemsetAsync(sums, 0, 10 * sizeof(double), stream);

    // level 0: streaming kernel, r10-proven grid (2 strips x 8 segs x 48 = 768)
    hipLaunchKernelGGL(msssim_stream_l0, dim3(2, 8, 48), dim3(256), 0, stream,
                       img1, img2, sums, X1, X2);

    // levels 1-4: phase kernel; L1 segs=4 (r8-proven: 1536 blocks)
    auto launch_level = [&](const float* a, const float* b, int H, int level,
                            int segs, float* pa, float* pb) {
        const int Hout = H - HALO;
        const int strips = (Hout + TILE - 1) / TILE;
        const int ntiles = (Hout + TILE - 1) / TILE;
        const int tps = (ntiles + segs - 1) / segs;
        dim3 grid(strips, segs, 48);
        hipLaunchKernelGGL(msssim_level_kernel, grid, dim3(256), 0, stream,
                           a, b, H, level, tps, 1, sums, pa, pb);
    };

    launch_level(X1, X2, 256, 1, 4, Y1, Y2);          // level 1 -> (128)
    launch_level(Y1, Y2, 128, 2, 4, X1, X2);          // level 2 -> (64)
    launch_level(X1, X2, 64, 3, 2, Y1, Y2);           // level 3 -> (32)
    launch_level(Y1, Y2, 32, 4, 1, nullptr, nullptr); // level 4

    hipLaunchKernelGGL(msssim_final_kernel, dim3(1), dim3(64), 0, stream, sums, out);
}

// Round 13
// 151.562 us; speedup vs baseline: 1.1049x; 1.1049x over previous
//
#include <hip/hip_runtime.h>
#include <math.h>

typedef float vf2 __attribute__((ext_vector_type(2)));

// ---------------- packed dual-fp32 helpers (VOP3P) ----------------
__device__ __forceinline__ vf2 pk_fma(vf2 a, vf2 b, vf2 c) {
    vf2 d;
    asm("v_pk_fma_f32 %0, %1, %2, %3" : "=v"(d) : "v"(a), "v"(b), "v"(c));
    return d;
}
__device__ __forceinline__ vf2 pk_mul(vf2 a, vf2 b) {
    vf2 d;
    asm("v_pk_mul_f32 %0, %1, %2" : "=v"(d) : "v"(a), "v"(b));
    return d;
}
// weight-broadcast pk_fma: use LO (resp. HI) word of w for BOTH lanes.
// Verified numerically identical to pre-broadcast registers (r10 == r12 absmax).
__device__ __forceinline__ vf2 pk_fma_blo(vf2 w, vf2 b, vf2 c) {
    vf2 d;
    asm("v_pk_fma_f32 %0, %1, %2, %3 op_sel_hi:[0,1,1]"
        : "=v"(d) : "v"(w), "v"(b), "v"(c));
    return d;
}
__device__ __forceinline__ vf2 pk_fma_bhi(vf2 w, vf2 b, vf2 c) {
    vf2 d;
    asm("v_pk_fma_f32 %0, %1, %2, %3 op_sel:[1,0,0] op_sel_hi:[1,1,1]"
        : "=v"(d) : "v"(w), "v"(b), "v"(c));
    return d;
}

// ================= streaming level-0 kernel =================
// Thread owns output column ox = c0 + tid. Streams input rows in chunks of
// 11 (fully unrolled -> mod-11 register ring has static indices).
// CHUNK 0 IS PEELED with the scatter restricted to k <= j: without this,
// rows 0..9 pollute the slots of outputs orow 1..10 (their windows start
// below the segment) -- this was the r10..r12 absmax=5.9e-3 bug.
#define L0_H 512
#define L0_HOUT 502
#define L0_HP 256
#define L0_SEG 64
#define L0_NCHUNK 7                 // ceil((SEG+10)/11)
#define ROWW 536                    // 268 staged cols x (P,Q) words
#define NQ 134                      // quads per row
#define CARRY_BASE (11 * ROWW)      // 5896
#define STREAM_WORDS (CARRY_BASE + 2 * ROWW)   // + ping-pong carry

__global__ __launch_bounds__(256)
void msssim_stream_l0(const float* __restrict__ img1,
                      const float* __restrict__ img2,
                      double* __restrict__ sums,
                      float* __restrict__ poolP, float* __restrict__ poolQ)
{
    __shared__ __align__(16) float buf[STREAM_WORDS];
    __shared__ float wred[4][2];

    const float gs[11] = {0.00102838f, 0.00759875f, 0.03600077f, 0.10936070f,
                          0.21300554f, 0.26601173f, 0.21300554f, 0.10936070f,
                          0.03600077f, 0.00759875f, 0.00102838f};

    const int tid = threadIdx.x;
    const int c0 = blockIdx.x * 256;          // strip base col
    const int oy0 = blockIdx.y * L0_SEG;      // seg base output row
    const long long plane = (long long)blockIdx.z * L0_H * L0_H;
    const long long pplane = (long long)blockIdx.z * L0_HP * L0_HP;
    const bool colok = (c0 + tid) < L0_HOUT;

    // ---- weights: h taps (parity-shifted, 12) packed in 6 vf2;
    //      v taps (symmetric, 6 distinct) broadcast in 6 vf2
    const int par = tid & 1;
    vf2 wp[6];
    #pragma unroll
    for (int jq = 0; jq < 6; ++jq) {
        const int i0 = 2 * jq, i1 = 2 * jq + 1;
        const float we0 = (i0 < 11) ? gs[i0] : 0.f;
        const float wo0 = (i0 >= 1) ? gs[i0 - 1] : 0.f;
        const float we1 = (i1 < 11) ? gs[i1] : 0.f;
        const float wo1 = (i1 >= 1) ? gs[i1 - 1] : 0.f;
        wp[jq].x = par ? wo0 : we0;
        wp[jq].y = par ? wo1 : we1;
    }
    vf2 wgv[6];
    #pragma unroll
    for (int k = 0; k < 6; ++k) { wgv[k].x = gs[k]; wgv[k].y = gs[k]; }

    // ---- staging slots: 1474 quads (11 rows x 134), 6 slots/thread
    int rowS[6], colS[6], ldsoff[6], rHS[6];
    #pragma unroll
    for (int t = 0; t < 6; ++t) {
        const int s = tid + 256 * t;
        if (s < 11 * NQ) {
            const int r = s / NQ, q = s - NQ * r;
            rowS[t] = r;
            colS[t] = c0 + 2 * q;
            ldsoff[t] = r * ROWW + q * 4;
            rHS[t] = r * L0_H;
        } else { rowS[t] = -1; colS[t] = 0; ldsoff[t] = 0; rHS[t] = 0; }
    }

    float4 pf[6];
    auto prefetch = [&](int ybase) {
        const int yH = ybase * L0_H;
        #pragma unroll
        for (int t = 0; t < 6; ++t) {
            float2 a = make_float2(0.f, 0.f), b = make_float2(0.f, 0.f);
            if (rowS[t] >= 0) {
                const int y = ybase + rowS[t];
                if (y < L0_H && colS[t] < L0_H) {
                    const long long idx = plane + yH + rHS[t] + colS[t];
                    a = *(const float2*)(img1 + idx);
                    b = *(const float2*)(img2 + idx);
                }
            }
            pf[t] = make_float4(a.x + b.x, a.x - b.x, a.y + b.y, a.y - b.y);
        }
    };
    auto stage_write = [&]() {
        #pragma unroll
        for (int t = 0; t < 6; ++t)
            if (rowS[t] >= 0) *(float4*)&buf[ldsoff[t]] = pf[t];
    };

    // prologue: chunk 0
    prefetch(oy0);
    stage_write();
    __syncthreads();

    // ---- pending register ring
    vf2 pd_pq[11], pd_sq[11];
    #pragma unroll
    for (int s = 0; s < 11; ++s) { pd_pq[s] = (vf2){0.f, 0.f}; pd_sq[s] = (vf2){0.f, 0.f}; }

    const int qb4 = (tid >> 1) * 4;
    const float C1 = 4.0e-4f, C2 = 3.6e-3f;
    float ssim_acc = 0.f, cs_acc = 0.f;

    // ================= peeled chunk 0 (scatter limited to k <= j) =================
    {
        const int cs = oy0;                   // even (oy0 multiple of 64)

        prefetch(cs + 11);                    // chunk 1 loads

        if (tid < 128) {                      // pool: pairs (0,1)..(8,9)
            const int px = (c0 >> 1) + tid;
            const int t4 = tid * 4;
            #pragma unroll
            for (int jp = 0; jp <= 8; jp += 2) {
                const int py = (cs + jp) >> 1;
                if (py < L0_HP) {
                    const float4 v0 = *(const float4*)&buf[jp * ROWW + t4];
                    const float4 v1 = *(const float4*)&buf[(jp + 1) * ROWW + t4];
                    poolP[pplane + py * L0_HP + px] = 0.25f * (v0.x + v0.z + v1.x + v1.z);
                    poolQ[pplane + py * L0_HP + px] = 0.25f * (v0.y + v0.w + v1.y + v1.w);
                }
            }
        }
        if (tid < NQ) {                       // save row 10 for spanning pair of chunk 1
            *(float4*)&buf[CARRY_BASE + 0 * ROWW + tid * 4] =
                *(const float4*)&buf[10 * ROWW + tid * 4];
        }

        #pragma unroll
        for (int j = 0; j < 11; ++j) {
            float4 q[6];
            const int rw = j * ROWW + qb4;
            #pragma unroll
            for (int u = 0; u < 6; ++u) q[u] = *(const float4*)&buf[rw + 4 * u];

            vf2 hpq = {0.f, 0.f}, hsq = {0.f, 0.f};
            #pragma unroll
            for (int u = 0; u < 6; ++u) {
                const vf2 elo = {q[u].x, q[u].y};
                const vf2 ehi = {q[u].z, q[u].w};
                const vf2 slo = pk_mul(elo, elo);
                const vf2 shi = pk_mul(ehi, ehi);
                hpq = pk_fma_blo(wp[u], elo, hpq);
                hpq = pk_fma_bhi(wp[u], ehi, hpq);
                hsq = pk_fma_blo(wp[u], slo, hsq);
                hsq = pk_fma_bhi(wp[u], shi, hsq);
            }
            #pragma unroll
            for (int k = 0; k < 11; ++k) {
                if (k <= j) {                          // static: drop pre-window taps
                    const int s = (j - k + 11) % 11;   // static
                    const int m = (k <= 5) ? k : 10 - k;
                    pd_pq[s] = pk_fma(wgv[m], hpq, pd_pq[s]);
                    pd_sq[s] = pk_fma(wgv[m], hsq, pd_sq[s]);
                }
            }
            if (j == 10) {                    // emit orow 0 (slot 0)
                const int s = 0;
                if (oy0 < L0_HOUT && colok) {
                    const vf2 musq = pk_mul(pd_pq[s], pd_pq[s]);
                    const float sP = pd_sq[s].x - musq.x;
                    const float sQ = pd_sq[s].y - musq.y;
                    const float v1 = 0.5f * (sP - sQ) + C2;
                    const float v2 = 0.5f * (sP + sQ) + C2;
                    const float num1 = 0.5f * (musq.x - musq.y) + C1;
                    const float den1 = 0.5f * (musq.x + musq.y) + C1;
                    cs_acc += v1 * __builtin_amdgcn_rcpf(v2);
                    ssim_acc += num1 * v1 * __builtin_amdgcn_rcpf(den1 * v2);
                }
                pd_pq[s] = (vf2){0.f, 0.f};
                pd_sq[s] = (vf2){0.f, 0.f};
            }
        }

        __syncthreads();
        stage_write();                        // write chunk 1
        __syncthreads();
    }

    // ================= main chunks 1..NCHUNK-1 (r10 body) =================
    for (int c = 1; c < L0_NCHUNK; ++c) {
        const int cs = oy0 + 11 * c;
        const bool more = (c + 1 < L0_NCHUNK);

        if (more) prefetch(cs + 11);

        if (tid < 128) {
            const int px = (c0 >> 1) + tid;
            const int t4 = tid * 4;
            for (int jp = (cs & 1); jp + 1 <= 10; jp += 2) {
                const int py = (cs + jp) >> 1;
                if (py < L0_HP) {
                    const float4 v0 = *(const float4*)&buf[jp * ROWW + t4];
                    const float4 v1 = *(const float4*)&buf[(jp + 1) * ROWW + t4];
                    poolP[pplane + py * L0_HP + px] = 0.25f * (v0.x + v0.z + v1.x + v1.z);
                    poolQ[pplane + py * L0_HP + px] = 0.25f * (v0.y + v0.w + v1.y + v1.w);
                }
            }
            if (cs & 1) {                     // spanning pair (cs-1, cs)
                const int py = (cs - 1) >> 1;
                if (py < L0_HP) {
                    const float4 v0 = *(const float4*)&buf[CARRY_BASE + ((c - 1) & 1) * ROWW + t4];
                    const float4 v1 = *(const float4*)&buf[t4];
                    poolP[pplane + py * L0_HP + px] = 0.25f * (v0.x + v0.z + v1.x + v1.z);
                    poolQ[pplane + py * L0_HP + px] = 0.25f * (v0.y + v0.w + v1.y + v1.w);
                }
            }
        }
        if (((cs & 1) == 0) && more && tid < NQ) {
            *(float4*)&buf[CARRY_BASE + (c & 1) * ROWW + tid * 4] =
                *(const float4*)&buf[10 * ROWW + tid * 4];
        }

        #pragma unroll
        for (int j = 0; j < 11; ++j) {
            float4 q[6];
            const int rw = j * ROWW + qb4;
            #pragma unroll
            for (int u = 0; u < 6; ++u) q[u] = *(const float4*)&buf[rw + 4 * u];

            vf2 hpq = {0.f, 0.f}, hsq = {0.f, 0.f};
            #pragma unroll
            for (int u = 0; u < 6; ++u) {
                const vf2 elo = {q[u].x, q[u].y};
                const vf2 ehi = {q[u].z, q[u].w};
                const vf2 slo = pk_mul(elo, elo);
                const vf2 shi = pk_mul(ehi, ehi);
                hpq = pk_fma_blo(wp[u], elo, hpq);
                hpq = pk_fma_bhi(wp[u], ehi, hpq);
                hsq = pk_fma_blo(wp[u], slo, hsq);
                hsq = pk_fma_bhi(wp[u], shi, hsq);
            }
            #pragma unroll
            for (int k = 0; k < 11; ++k) {
                const int s = (j - k + 11) % 11;       // static
                const int m = (k <= 5) ? k : 10 - k;   // static
                pd_pq[s] = pk_fma(wgv[m], hpq, pd_pq[s]);
                pd_sq[s] = pk_fma(wgv[m], hsq, pd_sq[s]);
            }
            {
                const int yrel = 11 * c + j;           // >= 11 here
                const int s = (j + 1) % 11;            // static
                const int orow = yrel - 10;
                if (orow < L0_SEG && (oy0 + orow) < L0_HOUT && colok) {
                    const vf2 musq = pk_mul(pd_pq[s], pd_pq[s]);
                    const float sP = pd_sq[s].x - musq.x;
                    const float sQ = pd_sq[s].y - musq.y;
                    const float v1 = 0.5f * (sP - sQ) + C2;
                    const float v2 = 0.5f * (sP + sQ) + C2;
                    const float num1 = 0.5f * (musq.x - musq.y) + C1;
                    const float den1 = 0.5f * (musq.x + musq.y) + C1;
                    cs_acc += v1 * __builtin_amdgcn_rcpf(v2);
                    ssim_acc += num1 * v1 * __builtin_amdgcn_rcpf(den1 * v2);
                }
                pd_pq[s] = (vf2){0.f, 0.f};
                pd_sq[s] = (vf2){0.f, 0.f};
            }
        }

        __syncthreads();
        if (more) stage_write();
        __syncthreads();
    }

    // ---- block reduction + atomics (level 0)
    #pragma unroll
    for (int off = 32; off > 0; off >>= 1) {
        ssim_acc += __shfl_down(ssim_acc, off);
        cs_acc   += __shfl_down(cs_acc, off);
    }
    const int wave = tid >> 6;
    if ((tid & 63) == 0) { wred[wave][0] = ssim_acc; wred[wave][1] = cs_acc; }
    __syncthreads();
    if (tid == 0) {
        atomicAdd(&sums[0], (double)(wred[0][0] + wred[1][0] + wred[2][0] + wred[3][0]));
        atomicAdd(&sums[5], (double)(wred[0][1] + wred[1][1] + wred[2][1] + wred[3][1]));
    }
}

// ================= phase kernel for levels 1-4 (r9/r10, verbatim) =================
#define TILE 32
#define IN_DIM 42
#define SCP 21
#define HALO 10
#define STAGE_WORDS (IN_DIM * SCP * 4)
#define SH 340
#define HB STAGE_WORDS
#define SMEM_WORDS (HB + 16 * SH)

__global__ __launch_bounds__(256)
void msssim_level_kernel(const float* __restrict__ src1,
                         const float* __restrict__ src2,
                         int H, int level, int tiles_per_seg, int pq_input,
                         double* __restrict__ sums,
                         float* __restrict__ pool1, float* __restrict__ pool2)
{
    __shared__ __align__(16) float smem[SMEM_WORDS];
    __shared__ float wred[4][2];

    const float g[11] = {0.00102838f, 0.00759875f, 0.03600077f, 0.10936070f,
                         0.21300554f, 0.26601173f, 0.21300554f, 0.10936070f,
                         0.03600077f, 0.00759875f, 0.00102838f};
    vf2 wg[11];
    #pragma unroll
    for (int k = 0; k < 11; ++k) { wg[k].x = g[k]; wg[k].y = g[k]; }

    const int tid = threadIdx.x;
    const int Hout = H - HALO;
    const int ntiles = (Hout + TILE - 1) / TILE;
    const int tstart = blockIdx.y * tiles_per_seg;
    const int tend = min(ntiles, tstart + tiles_per_seg);
    const int ox0 = blockIdx.x * TILE;
    const int Hp = H >> 1;
    const long long base = (long long)blockIdx.z * H * H;

    int rHS[4], rS[4], xS[4];
    #pragma unroll
    for (int t4 = 0; t4 < 4; ++t4) {
        const int s = tid + 256 * t4;
        if (s < IN_DIM * SCP) {
            const int r = s / SCP, cp = s - r * SCP;
            rS[t4] = r; rHS[t4] = r * H; xS[t4] = ox0 + 2 * cp;
        } else { rS[t4] = -1; rHS[t4] = 0; xS[t4] = 0; }
    }

    auto load_slot = [&](int t4, int ybase) -> float4 {
        float2 a = make_float2(0.f, 0.f), b = make_float2(0.f, 0.f);
        if (rS[t4] >= 0) {
            const int y = ybase + rS[t4], x = xS[t4];
            if (y < H && x < H) {
                const long long idx = base + (long long)ybase * H + rHS[t4] + x;
                a = *(const float2*)(src1 + idx);
                b = *(const float2*)(src2 + idx);
            }
        }
        if (pq_input) return make_float4(a.x, b.x, a.y, b.y);
        return make_float4(a.x + b.x, a.x - b.x, a.y + b.y, a.y - b.y);
    };

    float4 pref[4];
    {
        #pragma unroll
        for (int t4 = 0; t4 < 4; ++t4) pref[t4] = load_slot(t4, tstart * TILE);
        #pragma unroll
        for (int t4 = 0; t4 < 4; ++t4)
            if (rS[t4] >= 0) *(float4*)&smem[(tid + 256 * t4) * 4] = pref[t4];
    }
    __syncthreads();

    float ssim_acc = 0.f, cs_acc = 0.f;

    for (int tt = tstart; tt < tend; ++tt) {
        const int ty0 = tt * TILE;
        const bool more = (tt + 1 < tend);

        if (more) {
            #pragma unroll
            for (int t4 = 0; t4 < 4; ++t4) pref[t4] = load_slot(t4, ty0 + TILE);
        }

        if (pool1 != nullptr) {
            const int pr = tid >> 4, pc = tid & 15;
            const int py = (ty0 >> 1) + pr, px = (ox0 >> 1) + pc;
            if (py < Hp && px < Hp) {
                const float4 v0 = *(const float4*)&smem[(2 * pr * SCP + pc) * 4];
                const float4 v1 = *(const float4*)&smem[((2 * pr + 1) * SCP + pc) * 4];
                const long long ob = (long long)blockIdx.z * Hp * Hp + (long long)py * Hp + px;
                pool1[ob] = 0.25f * (v0.x + v0.z + v1.x + v1.z);
                pool2[ob] = 0.25f * (v0.y + v0.w + v1.y + v1.w);
            }
        }

        float4 hA[3], hBv[3];
        #pragma unroll
        for (int t = 0; t < 3; ++t) {
            const int p = tid + 256 * t;
            if (p < IN_DIM * 16) {
                const int r = p >> 4, m = p & 15;
                vf2 Apq = {0.f, 0.f}, Asq = {0.f, 0.f};
                vf2 Bpq = {0.f, 0.f}, Bsq = {0.f, 0.f};
                #pragma unroll
                for (int jj = 0; jj < 6; ++jj) {
                    const float4 v = *(const float4*)&smem[(r * SCP + m + jj) * 4];
                    const vf2 lo = {v.x, v.y};
                    const vf2 hi = {v.z, v.w};
                    const vf2 losq = pk_mul(lo, lo);
                    const vf2 hisq = pk_mul(hi, hi);
                    Apq = pk_fma(wg[2 * jj], lo, Apq);
                    Asq = pk_fma(wg[2 * jj], losq, Asq);
                    if (jj >= 1) {
                        Bpq = pk_fma(wg[2 * jj - 1], lo, Bpq);
                        Bsq = pk_fma(wg[2 * jj - 1], losq, Bsq);
                    }
                    if (jj <= 4) {
                        Apq = pk_fma(wg[2 * jj + 1], hi, Apq);
                        Asq = pk_fma(wg[2 * jj + 1], hisq, Asq);
                    }
                    Bpq = pk_fma(wg[2 * jj], hi, Bpq);
                    Bsq = pk_fma(wg[2 * jj], hisq, Bsq);
                }
                hA[t]  = make_float4(Apq.x, Apq.y, Asq.x, Asq.y);
                hBv[t] = make_float4(Bpq.x, Bpq.y, Bsq.x, Bsq.y);
            }
        }
        __syncthreads();

        #pragma unroll
        for (int t = 0; t < 3; ++t) {
            const int p = tid + 256 * t;
            if (p < IN_DIM * 16) {
                const int r = p >> 4, m = p & 15;
                const int hb = HB + m * SH + r * 8;
                *(float4*)&smem[hb]     = hA[t];
                *(float4*)&smem[hb + 4] = hBv[t];
            }
        }
        if (more) {
            #pragma unroll
            for (int t4 = 0; t4 < 4; ++t4)
                if (rS[t4] >= 0) *(float4*)&smem[(tid + 256 * t4) * 4] = pref[t4];
        }
        __syncthreads();

        const int tx = tid & 31, rg = tid >> 5;
        const int r0 = rg * 4;
        const int m = tx >> 1, par = tx & 1;
        const int hb = HB + m * SH + par * 4;

        vf2 accPQ[4], accSQ[4];
        #pragma unroll
        for (int o = 0; o < 4; ++o) {
            accPQ[o] = (vf2){0.f, 0.f};
            accSQ[o] = (vf2){0.f, 0.f};
        }
        #pragma unroll
        for (int i = 0; i < 14; ++i) {
            const float4 h4 = *(const float4*)&smem[hb + (r0 + i) * 8];
            const vf2 ppq = {h4.x, h4.y};
            const vf2 psq = {h4.z, h4.w};
            #pragma unroll
            for (int o = 0; o < 4; ++o) {
                const int k = i - o;
                if (k >= 0 && k <= 10) {
                    accPQ[o] = pk_fma(wg[k], ppq, accPQ[o]);
                    accSQ[o] = pk_fma(wg[k], psq, accSQ[o]);
                }
            }
        }

        const float C1 = 4.0e-4f;
        const float C2 = 3.6e-3f;
        const int ox = ox0 + tx;
        #pragma unroll
        for (int o = 0; o < 4; ++o) {
            const int oy = ty0 + r0 + o;
            if (oy < Hout && ox < Hout) {
                const vf2 musq = pk_mul(accPQ[o], accPQ[o]);
                const float sP = accSQ[o].x - musq.x;
                const float sQ = accSQ[o].y - musq.y;
                const float v1 = 0.5f * (sP - sQ) + C2;
                const float v2 = 0.5f * (sP + sQ) + C2;
                const float num1 = 0.5f * (musq.x - musq.y) + C1;
                const float den1 = 0.5f * (musq.x + musq.y) + C1;
                cs_acc += v1 * __builtin_amdgcn_rcpf(v2);
                ssim_acc += num1 * v1 * __builtin_amdgcn_rcpf(den1 * v2);
            }
        }
    }

    #pragma unroll
    for (int off = 32; off > 0; off >>= 1) {
        ssim_acc += __shfl_down(ssim_acc, off);
        cs_acc   += __shfl_down(cs_acc, off);
    }
    const int wave = tid >> 6;
    if ((tid & 63) == 0) { wred[wave][0] = ssim_acc; wred[wave][1] = cs_acc; }
    __syncthreads();
    if (tid == 0) {
        const float s = wred[0][0] + wred[1][0] + wred[2][0] + wred[3][0];
        const float c = wred[0][1] + wred[1][1] + wred[2][1] + wred[3][1];
        atomicAdd(&sums[level],     (double)s);
        atomicAdd(&sums[5 + level], (double)c);
    }
}

// -------------------- final combine --------------------
__global__ void msssim_final_kernel(const double* __restrict__ sums,
                                    float* __restrict__ out)
{
    if (threadIdx.x == 0 && blockIdx.x == 0) {
        const double W[5] = {0.0448, 0.2856, 0.3001, 0.2363, 0.1333};
        const int Houts[5] = {502, 246, 118, 54, 22};
        double mssim[5], mcs[5];
        for (int l = 0; l < 5; ++l) {
            const double cnt = 48.0 * (double)Houts[l] * (double)Houts[l];
            mssim[l] = (sums[l]     / cnt + 1.0) * 0.5;
            mcs[l]   = (sums[5 + l] / cnt + 1.0) * 0.5;
        }
        const double p2 = pow(mssim[4], W[4]);
        double prod = 1.0;
        for (int l = 0; l < 4; ++l) prod *= pow(mcs[l], W[l]) * p2;
        out[0] = (float)(1.0 - prod);
    }
}

// -------------------- launch --------------------
extern "C" void kernel_launch(void* const* d_in, const int* in_sizes, int n_in,
                              void* d_out, int out_size, void* d_ws, size_t ws_size,
                              hipStream_t stream)
{
    const float* img1 = (const float*)d_in[0];
    const float* img2 = (const float*)d_in[1];
    float* out = (float*)d_out;
    (void)in_sizes; (void)n_in; (void)out_size; (void)ws_size;

    char* ws = (char*)d_ws;
    double* sums = (double*)ws;                      // 10 doubles
    float* X1 = (float*)(ws + 256);                  // P planes (L1 input)
    float* X2 = X1 + 3145728;                        // Q planes
    float* Y1 = X2 + 3145728;
    float* Y2 = Y1 + 786432;

    hipMemsetAsync(sums, 0, 10 * sizeof(double), stream);

    // level 0: streaming kernel, r10-proven grid (2 strips x 8 segs x 48 = 768)
    hipLaunchKernelGGL(msssim_stream_l0, dim3(2, 8, 48), dim3(256), 0, stream,
                       img1, img2, sums, X1, X2);

    // levels 1-4: phase kernel, r10-proven seg config
    auto launch_level = [&](const float* a, const float* b, int H, int level,
                            int segs, float* pa, float* pb) {
        const int Hout = H - HALO;
        const int strips = (Hout + TILE - 1) / TILE;
        const int ntiles = (Hout + TILE - 1) / TILE;
        const int tps = (ntiles + segs - 1) / segs;
        dim3 grid(strips, segs, 48);
        hipLaunchKernelGGL(msssim_level_kernel, grid, dim3(256), 0, stream,
                           a, b, H, level, tps, 1, sums, pa, pb);
    };

    launch_level(X1, X2, 256, 1, 2, Y1, Y2);          // level 1 -> (128)
    launch_level(Y1, Y2, 128, 2, 4, X1, X2);          // level 2 -> (64)
    launch_level(X1, X2, 64, 3, 2, Y1, Y2);           // level 3 -> (32)
    launch_level(Y1, Y2, 32, 4, 1, nullptr, nullptr); // level 4

    hipLaunchKernelGGL(msssim_final_kernel, dim3(1), dim3(64), 0, stream, sums, out);
}

// Round 14
// 142.702 us; speedup vs baseline: 1.1735x; 1.0621x over previous
//
#include <hip/hip_runtime.h>
#include <math.h>

typedef float vf2 __attribute__((ext_vector_type(2)));

// ---------------- packed dual-fp32 helpers (VOP3P) ----------------
__device__ __forceinline__ vf2 pk_fma(vf2 a, vf2 b, vf2 c) {
    vf2 d;
    asm("v_pk_fma_f32 %0, %1, %2, %3" : "=v"(d) : "v"(a), "v"(b), "v"(c));
    return d;
}
__device__ __forceinline__ vf2 pk_mul(vf2 a, vf2 b) {
    vf2 d;
    asm("v_pk_mul_f32 %0, %1, %2" : "=v"(d) : "v"(a), "v"(b));
    return d;
}
// weight-broadcast pk_fma: use LO (resp. HI) word of w for BOTH lanes.
__device__ __forceinline__ vf2 pk_fma_blo(vf2 w, vf2 b, vf2 c) {
    vf2 d;
    asm("v_pk_fma_f32 %0, %1, %2, %3 op_sel_hi:[0,1,1]"
        : "=v"(d) : "v"(w), "v"(b), "v"(c));
    return d;
}
__device__ __forceinline__ vf2 pk_fma_bhi(vf2 w, vf2 b, vf2 c) {
    vf2 d;
    asm("v_pk_fma_f32 %0, %1, %2, %3 op_sel:[1,0,0] op_sel_hi:[1,1,1]"
        : "=v"(d) : "v"(w), "v"(b), "v"(c));
    return d;
}

// ================= streaming level-0 kernel =================
// Thread owns output column ox = c0 + tid. Streams input rows in chunks of
// 11 (fully unrolled -> mod-11 register ring has static indices).
// RING DISCIPLINE (r13->r14): slot j%11 is reset at the START of row j,
// BEFORE the scatter (not after emit). Steady-state no-op (the slot emitted
// at end of row j-1 is exactly slot j%11), but in chunk 0 it kills the
// pre-window pollution that caused the r10..r12 absmax=5.9e-3 bug --
// without the r13 peel's code/VGPR cost.
#define L0_H 512
#define L0_HOUT 502
#define L0_HP 256
#define L0_SEG 64
#define L0_NCHUNK 7                 // ceil((SEG+10)/11)
#define ROWW 536                    // 268 staged cols x (P,Q) words
#define NQ 134                      // quads per row
#define CARRY_BASE (11 * ROWW)      // 5896
#define STREAM_WORDS (CARRY_BASE + 2 * ROWW)   // + ping-pong carry

__global__ __launch_bounds__(256)
void msssim_stream_l0(const float* __restrict__ img1,
                      const float* __restrict__ img2,
                      double* __restrict__ sums,
                      float* __restrict__ poolP, float* __restrict__ poolQ)
{
    __shared__ __align__(16) float buf[STREAM_WORDS];
    __shared__ float wred[4][2];

    const float gs[11] = {0.00102838f, 0.00759875f, 0.03600077f, 0.10936070f,
                          0.21300554f, 0.26601173f, 0.21300554f, 0.10936070f,
                          0.03600077f, 0.00759875f, 0.00102838f};

    const int tid = threadIdx.x;
    const int c0 = blockIdx.x * 256;          // strip base col
    const int oy0 = blockIdx.y * L0_SEG;      // seg base output row
    const long long plane = (long long)blockIdx.z * L0_H * L0_H;
    const long long pplane = (long long)blockIdx.z * L0_HP * L0_HP;
    const bool colok = (c0 + tid) < L0_HOUT;

    // ---- weights: h taps (parity-shifted, 12) packed in 6 vf2;
    //      v taps (symmetric, 6 distinct) broadcast in 6 vf2
    const int par = tid & 1;
    vf2 wp[6];
    #pragma unroll
    for (int jq = 0; jq < 6; ++jq) {
        const int i0 = 2 * jq, i1 = 2 * jq + 1;
        const float we0 = (i0 < 11) ? gs[i0] : 0.f;
        const float wo0 = (i0 >= 1) ? gs[i0 - 1] : 0.f;
        const float we1 = (i1 < 11) ? gs[i1] : 0.f;
        const float wo1 = (i1 >= 1) ? gs[i1 - 1] : 0.f;
        wp[jq].x = par ? wo0 : we0;
        wp[jq].y = par ? wo1 : we1;
    }
    vf2 wgv[6];
    #pragma unroll
    for (int k = 0; k < 6; ++k) { wgv[k].x = gs[k]; wgv[k].y = gs[k]; }

    // ---- staging slots: 1474 quads (11 rows x 134), 6 slots/thread
    int rowS[6], colS[6], ldsoff[6], rHS[6];
    #pragma unroll
    for (int t = 0; t < 6; ++t) {
        const int s = tid + 256 * t;
        if (s < 11 * NQ) {
            const int r = s / NQ, q = s - NQ * r;
            rowS[t] = r;
            colS[t] = c0 + 2 * q;
            ldsoff[t] = r * ROWW + q * 4;
            rHS[t] = r * L0_H;
        } else { rowS[t] = -1; colS[t] = 0; ldsoff[t] = 0; rHS[t] = 0; }
    }

    float4 pf[6];
    auto prefetch = [&](int ybase) {
        const int yH = ybase * L0_H;
        #pragma unroll
        for (int t = 0; t < 6; ++t) {
            float2 a = make_float2(0.f, 0.f), b = make_float2(0.f, 0.f);
            if (rowS[t] >= 0) {
                const int y = ybase + rowS[t];
                if (y < L0_H && colS[t] < L0_H) {
                    const long long idx = plane + yH + rHS[t] + colS[t];
                    a = *(const float2*)(img1 + idx);
                    b = *(const float2*)(img2 + idx);
                }
            }
            pf[t] = make_float4(a.x + b.x, a.x - b.x, a.y + b.y, a.y - b.y);
        }
    };
    auto stage_write = [&]() {
        #pragma unroll
        for (int t = 0; t < 6; ++t)
            if (rowS[t] >= 0) *(float4*)&buf[ldsoff[t]] = pf[t];
    };

    // prologue: chunk 0
    prefetch(oy0);
    stage_write();
    __syncthreads();

    // ---- pending register ring
    vf2 pd_pq[11], pd_sq[11];
    #pragma unroll
    for (int s = 0; s < 11; ++s) { pd_pq[s] = (vf2){0.f, 0.f}; pd_sq[s] = (vf2){0.f, 0.f}; }

    const int qb4 = (tid >> 1) * 4;
    const float C1 = 4.0e-4f, C2 = 3.6e-3f;
    float ssim_acc = 0.f, cs_acc = 0.f;

    for (int c = 0; c < L0_NCHUNK; ++c) {
        const int cs = oy0 + 11 * c;          // first input row of chunk
        const bool more = (c + 1 < L0_NCHUNK);

        if (more) prefetch(cs + 11);          // loads hide under compute

        // ---- fused pool of (P,Q) rows (pairs inside chunk + spanning)
        if (tid < 128) {
            const int px = (c0 >> 1) + tid;
            const int t4 = tid * 4;
            for (int jp = (cs & 1); jp + 1 <= 10; jp += 2) {
                const int py = (cs + jp) >> 1;
                if (py < L0_HP) {
                    const float4 v0 = *(const float4*)&buf[jp * ROWW + t4];
                    const float4 v1 = *(const float4*)&buf[(jp + 1) * ROWW + t4];
                    poolP[pplane + py * L0_HP + px] = 0.25f * (v0.x + v0.z + v1.x + v1.z);
                    poolQ[pplane + py * L0_HP + px] = 0.25f * (v0.y + v0.w + v1.y + v1.w);
                }
            }
            if (c > 0 && (cs & 1)) {          // spanning pair (cs-1, cs)
                const int py = (cs - 1) >> 1;
                if (py < L0_HP) {
                    const float4 v0 = *(const float4*)&buf[CARRY_BASE + ((c - 1) & 1) * ROWW + t4];
                    const float4 v1 = *(const float4*)&buf[t4];
                    poolP[pplane + py * L0_HP + px] = 0.25f * (v0.x + v0.z + v1.x + v1.z);
                    poolQ[pplane + py * L0_HP + px] = 0.25f * (v0.y + v0.w + v1.y + v1.w);
                }
            }
        }
        if (((cs & 1) == 0) && more && tid < NQ) {   // next chunk spans: save last row
            *(float4*)&buf[CARRY_BASE + (c & 1) * ROWW + tid * 4] =
                *(const float4*)&buf[10 * ROWW + tid * 4];
        }

        // ---- 11 unrolled rows: reset slot j -> h -> scatter -> emit
        #pragma unroll
        for (int j = 0; j < 11; ++j) {
            // reset the slot whose new output's first tap (k=0) is this row.
            // Steady-state: this slot was emitted at end of previous row.
            // Chunk 0: this kills pre-window pollution (correctness fix).
            pd_pq[j] = (vf2){0.f, 0.f};
            pd_sq[j] = (vf2){0.f, 0.f};

            float4 q[6];
            const int rw = j * ROWW + qb4;
            #pragma unroll
            for (int u = 0; u < 6; ++u) q[u] = *(const float4*)&buf[rw + 4 * u];

            vf2 hpq = {0.f, 0.f}, hsq = {0.f, 0.f};
            #pragma unroll
            for (int u = 0; u < 6; ++u) {
                const vf2 elo = {q[u].x, q[u].y};
                const vf2 ehi = {q[u].z, q[u].w};
                const vf2 slo = pk_mul(elo, elo);
                const vf2 shi = pk_mul(ehi, ehi);
                hpq = pk_fma_blo(wp[u], elo, hpq);
                hpq = pk_fma_bhi(wp[u], ehi, hpq);
                hsq = pk_fma_blo(wp[u], slo, hsq);
                hsq = pk_fma_bhi(wp[u], shi, hsq);
            }
            #pragma unroll
            for (int k = 0; k < 11; ++k) {
                const int s = (j - k + 11) % 11;       // static
                const int m = (k <= 5) ? k : 10 - k;   // static
                pd_pq[s] = pk_fma(wgv[m], hpq, pd_pq[s]);
                pd_sq[s] = pk_fma(wgv[m], hsq, pd_sq[s]);
            }
            const int yrel = 11 * c + j;
            if (yrel >= 10) {
                const int s = (j + 1) % 11;            // static
                const int orow = yrel - 10;
                if (orow < L0_SEG && (oy0 + orow) < L0_HOUT && colok) {
                    const vf2 musq = pk_mul(pd_pq[s], pd_pq[s]);  // (cP^2,cQ^2)
                    const float sP = pd_sq[s].x - musq.x;
                    const float sQ = pd_sq[s].y - musq.y;
                    const float v1 = 0.5f * (sP - sQ) + C2;
                    const float v2 = 0.5f * (sP + sQ) + C2;
                    const float num1 = 0.5f * (musq.x - musq.y) + C1;
                    const float den1 = 0.5f * (musq.x + musq.y) + C1;
                    cs_acc += v1 * __builtin_amdgcn_rcpf(v2);
                    ssim_acc += num1 * v1 * __builtin_amdgcn_rcpf(den1 * v2);
                }
                // no reset here: slot is reset at the start of the next row
            }
        }

        __syncthreads();              // all buf reads done
        if (more) stage_write();      // write chunk c+1
        __syncthreads();              // buf ready
    }

    // ---- block reduction + atomics (level 0)
    #pragma unroll
    for (int off = 32; off > 0; off >>= 1) {
        ssim_acc += __shfl_down(ssim_acc, off);
        cs_acc   += __shfl_down(cs_acc, off);
    }
    const int wave = tid >> 6;
    if ((tid & 63) == 0) { wred[wave][0] = ssim_acc; wred[wave][1] = cs_acc; }
    __syncthreads();
    if (tid == 0) {
        atomicAdd(&sums[0], (double)(wred[0][0] + wred[1][0] + wred[2][0] + wred[3][0]));
        atomicAdd(&sums[5], (double)(wred[0][1] + wred[1][1] + wred[2][1] + wred[3][1]));
    }
}

// ================= phase kernel for levels 1-4 (r9/r10, verbatim) =================
#define TILE 32
#define IN_DIM 42
#define SCP 21
#define HALO 10
#define STAGE_WORDS (IN_DIM * SCP * 4)
#define SH 340
#define HB STAGE_WORDS
#define SMEM_WORDS (HB + 16 * SH)

__global__ __launch_bounds__(256)
void msssim_level_kernel(const float* __restrict__ src1,
                         const float* __restrict__ src2,
                         int H, int level, int tiles_per_seg, int pq_input,
                         double* __restrict__ sums,
                         float* __restrict__ pool1, float* __restrict__ pool2)
{
    __shared__ __align__(16) float smem[SMEM_WORDS];
    __shared__ float wred[4][2];

    const float g[11] = {0.00102838f, 0.00759875f, 0.03600077f, 0.10936070f,
                         0.21300554f, 0.26601173f, 0.21300554f, 0.10936070f,
                         0.03600077f, 0.00759875f, 0.00102838f};
    vf2 wg[11];
    #pragma unroll
    for (int k = 0; k < 11; ++k) { wg[k].x = g[k]; wg[k].y = g[k]; }

    const int tid = threadIdx.x;
    const int Hout = H - HALO;
    const int ntiles = (Hout + TILE - 1) / TILE;
    const int tstart = blockIdx.y * tiles_per_seg;
    const int tend = min(ntiles, tstart + tiles_per_seg);
    const int ox0 = blockIdx.x * TILE;
    const int Hp = H >> 1;
    const long long base = (long long)blockIdx.z * H * H;

    int rHS[4], rS[4], xS[4];
    #pragma unroll
    for (int t4 = 0; t4 < 4; ++t4) {
        const int s = tid + 256 * t4;
        if (s < IN_DIM * SCP) {
            const int r = s / SCP, cp = s - r * SCP;
            rS[t4] = r; rHS[t4] = r * H; xS[t4] = ox0 + 2 * cp;
        } else { rS[t4] = -1; rHS[t4] = 0; xS[t4] = 0; }
    }

    auto load_slot = [&](int t4, int ybase) -> float4 {
        float2 a = make_float2(0.f, 0.f), b = make_float2(0.f, 0.f);
        if (rS[t4] >= 0) {
            const int y = ybase + rS[t4], x = xS[t4];
            if (y < H && x < H) {
                const long long idx = base + (long long)ybase * H + rHS[t4] + x;
                a = *(const float2*)(src1 + idx);
                b = *(const float2*)(src2 + idx);
            }
        }
        if (pq_input) return make_float4(a.x, b.x, a.y, b.y);
        return make_float4(a.x + b.x, a.x - b.x, a.y + b.y, a.y - b.y);
    };

    float4 pref[4];
    {
        #pragma unroll
        for (int t4 = 0; t4 < 4; ++t4) pref[t4] = load_slot(t4, tstart * TILE);
        #pragma unroll
        for (int t4 = 0; t4 < 4; ++t4)
            if (rS[t4] >= 0) *(float4*)&smem[(tid + 256 * t4) * 4] = pref[t4];
    }
    __syncthreads();

    float ssim_acc = 0.f, cs_acc = 0.f;

    for (int tt = tstart; tt < tend; ++tt) {
        const int ty0 = tt * TILE;
        const bool more = (tt + 1 < tend);

        if (more) {
            #pragma unroll
            for (int t4 = 0; t4 < 4; ++t4) pref[t4] = load_slot(t4, ty0 + TILE);
        }

        if (pool1 != nullptr) {
            const int pr = tid >> 4, pc = tid & 15;
            const int py = (ty0 >> 1) + pr, px = (ox0 >> 1) + pc;
            if (py < Hp && px < Hp) {
                const float4 v0 = *(const float4*)&smem[(2 * pr * SCP + pc) * 4];
                const float4 v1 = *(const float4*)&smem[((2 * pr + 1) * SCP + pc) * 4];
                const long long ob = (long long)blockIdx.z * Hp * Hp + (long long)py * Hp + px;
                pool1[ob] = 0.25f * (v0.x + v0.z + v1.x + v1.z);
                pool2[ob] = 0.25f * (v0.y + v0.w + v1.y + v1.w);
            }
        }

        float4 hA[3], hBv[3];
        #pragma unroll
        for (int t = 0; t < 3; ++t) {
            const int p = tid + 256 * t;
            if (p < IN_DIM * 16) {
                const int r = p >> 4, m = p & 15;
                vf2 Apq = {0.f, 0.f}, Asq = {0.f, 0.f};
                vf2 Bpq = {0.f, 0.f}, Bsq = {0.f, 0.f};
                #pragma unroll
                for (int jj = 0; jj < 6; ++jj) {
                    const float4 v = *(const float4*)&smem[(r * SCP + m + jj) * 4];
                    const vf2 lo = {v.x, v.y};
                    const vf2 hi = {v.z, v.w};
                    const vf2 losq = pk_mul(lo, lo);
                    const vf2 hisq = pk_mul(hi, hi);
                    Apq = pk_fma(wg[2 * jj], lo, Apq);
                    Asq = pk_fma(wg[2 * jj], losq, Asq);
                    if (jj >= 1) {
                        Bpq = pk_fma(wg[2 * jj - 1], lo, Bpq);
                        Bsq = pk_fma(wg[2 * jj - 1], losq, Bsq);
                    }
                    if (jj <= 4) {
                        Apq = pk_fma(wg[2 * jj + 1], hi, Apq);
                        Asq = pk_fma(wg[2 * jj + 1], hisq, Asq);
                    }
                    Bpq = pk_fma(wg[2 * jj], hi, Bpq);
                    Bsq = pk_fma(wg[2 * jj], hisq, Bsq);
                }
                hA[t]  = make_float4(Apq.x, Apq.y, Asq.x, Asq.y);
                hBv[t] = make_float4(Bpq.x, Bpq.y, Bsq.x, Bsq.y);
            }
        }
        __syncthreads();

        #pragma unroll
        for (int t = 0; t < 3; ++t) {
            const int p = tid + 256 * t;
            if (p < IN_DIM * 16) {
                const int r = p >> 4, m = p & 15;
                const int hb = HB + m * SH + r * 8;
                *(float4*)&smem[hb]     = hA[t];
                *(float4*)&smem[hb + 4] = hBv[t];
            }
        }
        if (more) {
            #pragma unroll
            for (int t4 = 0; t4 < 4; ++t4)
                if (rS[t4] >= 0) *(float4*)&smem[(tid + 256 * t4) * 4] = pref[t4];
        }
        __syncthreads();

        const int tx = tid & 31, rg = tid >> 5;
        const int r0 = rg * 4;
        const int m = tx >> 1, par = tx & 1;
        const int hb = HB + m * SH + par * 4;

        vf2 accPQ[4], accSQ[4];
        #pragma unroll
        for (int o = 0; o < 4; ++o) {
            accPQ[o] = (vf2){0.f, 0.f};
            accSQ[o] = (vf2){0.f, 0.f};
        }
        #pragma unroll
        for (int i = 0; i < 14; ++i) {
            const float4 h4 = *(const float4*)&smem[hb + (r0 + i) * 8];
            const vf2 ppq = {h4.x, h4.y};
            const vf2 psq = {h4.z, h4.w};
            #pragma unroll
            for (int o = 0; o < 4; ++o) {
                const int k = i - o;
                if (k >= 0 && k <= 10) {
                    accPQ[o] = pk_fma(wg[k], ppq, accPQ[o]);
                    accSQ[o] = pk_fma(wg[k], psq, accSQ[o]);
                }
            }
        }

        const float C1 = 4.0e-4f;
        const float C2 = 3.6e-3f;
        const int ox = ox0 + tx;
        #pragma unroll
        for (int o = 0; o < 4; ++o) {
            const int oy = ty0 + r0 + o;
            if (oy < Hout && ox < Hout) {
                const vf2 musq = pk_mul(accPQ[o], accPQ[o]);
                const float sP = accSQ[o].x - musq.x;
                const float sQ = accSQ[o].y - musq.y;
                const float v1 = 0.5f * (sP - sQ) + C2;
                const float v2 = 0.5f * (sP + sQ) + C2;
                const float num1 = 0.5f * (musq.x - musq.y) + C1;
                const float den1 = 0.5f * (musq.x + musq.y) + C1;
                cs_acc += v1 * __builtin_amdgcn_rcpf(v2);
                ssim_acc += num1 * v1 * __builtin_amdgcn_rcpf(den1 * v2);
            }
        }
    }

    #pragma unroll
    for (int off = 32; off > 0; off >>= 1) {
        ssim_acc += __shfl_down(ssim_acc, off);
        cs_acc   += __shfl_down(cs_acc, off);
    }
    const int wave = tid >> 6;
    if ((tid & 63) == 0) { wred[wave][0] = ssim_acc; wred[wave][1] = cs_acc; }
    __syncthreads();
    if (tid == 0) {
        const float s = wred[0][0] + wred[1][0] + wred[2][0] + wred[3][0];
        const float c = wred[0][1] + wred[1][1] + wred[2][1] + wred[3][1];
        atomicAdd(&sums[level],     (double)s);
        atomicAdd(&sums[5 + level], (double)c);
    }
}

// -------------------- final combine --------------------
__global__ void msssim_final_kernel(const double* __restrict__ sums,
                                    float* __restrict__ out)
{
    if (threadIdx.x == 0 && blockIdx.x == 0) {
        const double W[5] = {0.0448, 0.2856, 0.3001, 0.2363, 0.1333};
        const int Houts[5] = {502, 246, 118, 54, 22};
        double mssim[5], mcs[5];
        for (int l = 0; l < 5; ++l) {
            const double cnt = 48.0 * (double)Houts[l] * (double)Houts[l];
            mssim[l] = (sums[l]     / cnt + 1.0) * 0.5;
            mcs[l]   = (sums[5 + l] / cnt + 1.0) * 0.5;
        }
        const double p2 = pow(mssim[4], W[4]);
        double prod = 1.0;
        for (int l = 0; l < 4; ++l) prod *= pow(mcs[l], W[l]) * p2;
        out[0] = (float)(1.0 - prod);
    }
}

// -------------------- launch --------------------
extern "C" void kernel_launch(void* const* d_in, const int* in_sizes, int n_in,
                              void* d_out, int out_size, void* d_ws, size_t ws_size,
                              hipStream_t stream)
{
    const float* img1 = (const float*)d_in[0];
    const float* img2 = (const float*)d_in[1];
    float* out = (float*)d_out;
    (void)in_sizes; (void)n_in; (void)out_size; (void)ws_size;

    char* ws = (char*)d_ws;
    double* sums = (double*)ws;                      // 10 doubles
    float* X1 = (float*)(ws + 256);                  // P planes (L1 input)
    float* X2 = X1 + 3145728;                        // Q planes
    float* Y1 = X2 + 3145728;
    float* Y2 = Y1 + 786432;

    hipMemsetAsync(sums, 0, 10 * sizeof(double), stream);

    // level 0: streaming kernel, r10-proven grid (2 strips x 8 segs x 48 = 768)
    hipLaunchKernelGGL(msssim_stream_l0, dim3(2, 8, 48), dim3(256), 0, stream,
                       img1, img2, sums, X1, X2);

    // levels 1-4: phase kernel, r10-proven seg config
    auto launch_level = [&](const float* a, const float* b, int H, int level,
                            int segs, float* pa, float* pb) {
        const int Hout = H - HALO;
        const int strips = (Hout + TILE - 1) / TILE;
        const int ntiles = (Hout + TILE - 1) / TILE;
        const int tps = (ntiles + segs - 1) / segs;
        dim3 grid(strips, segs, 48);
        hipLaunchKernelGGL(msssim_level_kernel, grid, dim3(256), 0, stream,
                           a, b, H, level, tps, 1, sums, pa, pb);
    };

    launch_level(X1, X2, 256, 1, 2, Y1, Y2);          // level 1 -> (128)
    launch_level(Y1, Y2, 128, 2, 4, X1, X2);          // level 2 -> (64)
    launch_level(X1, X2, 64, 3, 2, Y1, Y2);           // level 3 -> (32)
    launch_level(Y1, Y2, 32, 4, 1, nullptr, nullptr); // level 4

    hipLaunchKernelGGL(msssim_final_kernel, dim3(1), dim3(64), 0, stream, sums, out);
}